// Round 1
// baseline (909.775 us; speedup 1.0000x reference)
//
#include <hip/hip_runtime.h>
#include <math.h>

constexpr int B  = 4;
constexpr int S  = 12;
constexpr int N  = 20000;
constexpr int HD = 64;
constexpr int E0 = 640000;
constexpr int EL = E0 + N;      // edges + self loops
constexpr int BN = B * N;

// ---------------- CSR build (edges -> per-dst lists) ----------------
__global__ void count_kernel(const int* __restrict__ ei, int* __restrict__ count) {
    int e = blockIdx.x * blockDim.x + threadIdx.x;
    if (e >= EL) return;
    int d = (e < E0) ? ei[E0 + e] : (e - E0);
    atomicAdd(&count[d], 1);
}

// single block 256 threads: inclusive scan of count -> offsets[1..N], cursor=exclusive
__global__ void scan_kernel(int* __restrict__ cursor /*in: count, out: start*/,
                            int* __restrict__ offsets) {
    __shared__ int wsum[4];
    int lane = threadIdx.x & 63, wid = threadIdx.x >> 6;
    int carry = 0;
    if (threadIdx.x == 0) offsets[0] = 0;
    for (int base = 0; base < N; base += 256) {
        int i = base + threadIdx.x;
        int v = (i < N) ? cursor[i] : 0;
        int x = v;
        #pragma unroll
        for (int d = 1; d < 64; d <<= 1) {
            int y = __shfl_up(x, d, 64);
            if (lane >= d) x += y;
        }
        if (lane == 63) wsum[wid] = x;
        __syncthreads();
        int woff = 0;
        for (int w = 0; w < wid; ++w) woff += wsum[w];
        int incl = carry + woff + x;
        if (i < N) { offsets[i + 1] = incl; cursor[i] = incl - v; }
        int total = wsum[0] + wsum[1] + wsum[2] + wsum[3];
        __syncthreads();               // protect wsum before next chunk writes
        carry += total;
    }
}

__global__ void scatter_kernel(const int* __restrict__ ei, int* __restrict__ cursor,
                               int* __restrict__ perm_src) {
    int e = blockIdx.x * blockDim.x + threadIdx.x;
    if (e >= EL) return;
    int s, d;
    if (e < E0) { s = ei[e]; d = ei[E0 + e]; }
    else        { s = e - E0; d = s; }
    int pos = atomicAdd(&cursor[d], 1);
    perm_src[pos] = s;
}

// ---------------- projection: h[b,n,k] = sum_s x[b,s,n] * w[s,k] + b[k] -------
__global__ __launch_bounds__(256, 1)
void proj_kernel(const float* __restrict__ x, const float* __restrict__ w,
                 const float* __restrict__ bias, float* __restrict__ out) {
    int t = blockIdx.x * blockDim.x + threadIdx.x;
    if (t >= BN) return;
    int bb = t / N, n = t - bb * N;
    const float* xp = x + (size_t)bb * S * N + n;
    float xs[S];
    #pragma unroll
    for (int s = 0; s < S; ++s) xs[s] = xp[(size_t)s * N];
    float acc[HD];
    #pragma unroll
    for (int k = 0; k < HD; ++k) acc[k] = bias[k];
    #pragma unroll
    for (int s = 0; s < S; ++s) {
        #pragma unroll
        for (int k = 0; k < HD; ++k) acc[k] = fmaf(xs[s], w[s * HD + k], acc[k]);
    }
    float4* op = (float4*)(out + (size_t)t * HD);
    #pragma unroll
    for (int q = 0; q < HD / 4; ++q)
        op[q] = make_float4(acc[4*q], acc[4*q+1], acc[4*q+2], acc[4*q+3]);
}

// ------- xe = h @ w ; es[n,h]=dot(xe[n,h,:],asrc[h]); ed likewise ------------
template<int H>
__global__ __launch_bounds__(256, 1)
void gemm_attn_kernel(const float* __restrict__ hin, const float* __restrict__ w,
                      const float* __restrict__ asrc, const float* __restrict__ adst,
                      float* __restrict__ xe, float* __restrict__ es, float* __restrict__ ed) {
    constexpr int C = HD / H;
    int t = blockIdx.x * blockDim.x + threadIdx.x;
    if (t >= BN) return;
    const float4* rp = (const float4*)(hin + (size_t)t * HD);
    float acc[HD];
    #pragma unroll
    for (int k = 0; k < HD; ++k) acc[k] = 0.f;
    for (int c0 = 0; c0 < HD; c0 += 8) {        // not unrolled: 8 iters, 512 FMA body
        float4 v0 = rp[c0 / 4], v1 = rp[c0 / 4 + 1];
        float r8[8] = {v0.x, v0.y, v0.z, v0.w, v1.x, v1.y, v1.z, v1.w};
        #pragma unroll
        for (int j = 0; j < 8; ++j) {
            #pragma unroll
            for (int k = 0; k < HD; ++k)
                acc[k] = fmaf(r8[j], w[(c0 + j) * HD + k], acc[k]);
        }
    }
    float esa[H], eda[H];
    #pragma unroll
    for (int h = 0; h < H; ++h) { esa[h] = 0.f; eda[h] = 0.f; }
    #pragma unroll
    for (int k = 0; k < HD; ++k) {              // k = h*C + c matches [H,C] flatten
        esa[k / C] = fmaf(acc[k], asrc[k], esa[k / C]);
        eda[k / C] = fmaf(acc[k], adst[k], eda[k / C]);
    }
    float4* op = (float4*)(xe + (size_t)t * HD);
    #pragma unroll
    for (int q = 0; q < HD / 4; ++q)
        op[q] = make_float4(acc[4*q], acc[4*q+1], acc[4*q+2], acc[4*q+3]);
    #pragma unroll
    for (int h = 0; h < H; ++h) { es[t * H + h] = esa[h]; ed[t * H + h] = eda[h]; }
}

// ------- aggregation: one wave per (batch,node); lane = channel --------------
// out[i,c] = (sum_j p_j * xe[src_j, c]) / (sum_j p_j) + bias[c]
// p_j = exp(leaky_relu(es[src_j, h] + ed[i, h])), h = c / C
template<int H, bool DO_ELU>
__global__ __launch_bounds__(256, 4)
void agg_kernel(const float* __restrict__ xe, const float* __restrict__ es,
                const float* __restrict__ ed, const int* __restrict__ offsets,
                const int* __restrict__ perm_src, const float* __restrict__ bias,
                float* __restrict__ hout) {
    constexpr int C = HD / H;
    int wid = blockIdx.x * 4 + (threadIdx.x >> 6);
    if (wid >= BN) return;
    int lane = threadIdx.x & 63;
    int bb = wid / N, node = wid - bb * N;
    int off = offsets[node], end = offsets[node + 1];
    int h = lane / C;
    const float* es_b = es + (size_t)bb * N * H;
    const float* xe_b = xe + (size_t)bb * N * HD;
    float edv = ed[(size_t)(bb * N + node) * H + h];
    float acc = 0.f, ssum = 0.f;
    #pragma unroll 2
    for (int j = off; j < end; ++j) {
        int src = perm_src[j];                       // wave-uniform -> broadcast
        float e = es_b[src * H + h] + edv;
        e = (e > 0.f) ? e : 0.2f * e;                // leaky_relu 0.2
        float p = expf(e);
        ssum += p;
        acc = fmaf(p, xe_b[(size_t)src * HD + lane], acc);  // coalesced 256B gather
    }
    float r = acc / ssum + bias[lane];
    if (DO_ELU) r = (r > 0.f) ? r : expm1f(r);
    hout[(size_t)(bb * N + node) * HD + lane] = r;
}

// ------- conv1d(k=3 over node axis) + relu + 64->3 projection ----------------
__global__ __launch_bounds__(256, 1)
void conv_out_kernel(const float* __restrict__ h, const float* __restrict__ cw,
                     const float* __restrict__ cb, const float* __restrict__ ow,
                     const float* __restrict__ ob, float* __restrict__ out) {
    int t = blockIdx.x * blockDim.x + threadIdx.x;
    if (t >= BN) return;
    int bb = t / N, n = t - bb * N;
    float r[3][HD];
    #pragma unroll
    for (int dt = 0; dt < 3; ++dt) {
        int m = n + dt - 1;
        if (m >= 0 && m < N) {
            const float4* rp = (const float4*)(h + (size_t)(bb * N + m) * HD);
            #pragma unroll
            for (int q = 0; q < HD / 4; ++q) {
                float4 v = rp[q];
                r[dt][4*q] = v.x; r[dt][4*q+1] = v.y; r[dt][4*q+2] = v.z; r[dt][4*q+3] = v.w;
            }
        } else {
            #pragma unroll
            for (int k = 0; k < HD; ++k) r[dt][k] = 0.f;
        }
    }
    float p0 = ob[0], p1 = ob[1], p2 = ob[2];
    #pragma unroll 2
    for (int o = 0; o < HD; ++o) {
        const float* wo = cw + (size_t)o * HD * 3;
        float va = cb[o], vb = 0.f, vc = 0.f;       // 3 chains for ILP
        #pragma unroll
        for (int i = 0; i < HD; ++i) {
            va = fmaf(r[0][i], wo[i * 3 + 0], va);
            vb = fmaf(r[1][i], wo[i * 3 + 1], vb);
            vc = fmaf(r[2][i], wo[i * 3 + 2], vc);
        }
        float v = va + vb + vc;
        v = fmaxf(v, 0.f);
        p0 = fmaf(v, ow[o * 3 + 0], p0);
        p1 = fmaf(v, ow[o * 3 + 1], p1);
        p2 = fmaf(v, ow[o * 3 + 2], p2);
    }
    out[(size_t)bb * 3 * N + 0 * N + n] = p0;
    out[(size_t)bb * 3 * N + 1 * N + n] = p1;
    out[(size_t)bb * 3 * N + 2 * N + n] = p2;
}

extern "C" void kernel_launch(void* const* d_in, const int* in_sizes, int n_in,
                              void* d_out, int out_size, void* d_ws, size_t ws_size,
                              hipStream_t stream) {
    const float* x      = (const float*)d_in[0];
    const int*   ei     = (const int*)  d_in[1];
    const float* proj_w = (const float*)d_in[2];
    const float* proj_b = (const float*)d_in[3];
    const float* g_w [3] = {(const float*)d_in[4], (const float*)d_in[8],  (const float*)d_in[12]};
    const float* g_as[3] = {(const float*)d_in[5], (const float*)d_in[9],  (const float*)d_in[13]};
    const float* g_ad[3] = {(const float*)d_in[6], (const float*)d_in[10], (const float*)d_in[14]};
    const float* g_b [3] = {(const float*)d_in[7], (const float*)d_in[11], (const float*)d_in[15]};
    const float* conv_w = (const float*)d_in[16];
    const float* conv_b = (const float*)d_in[17];
    const float* out_w  = (const float*)d_in[18];
    const float* out_b  = (const float*)d_in[19];
    float* out = (float*)d_out;

    // workspace layout (fp32 elements)
    float* bufA = (float*)d_ws;                      // BN*HD
    float* bufX = bufA + (size_t)BN * HD;            // BN*HD
    float* es   = bufX + (size_t)BN * HD;            // BN*8 (max H)
    float* ed   = es   + (size_t)BN * 8;             // BN*8
    int* offsets = (int*)(ed + (size_t)BN * 8);      // N+1
    int* cursor  = offsets + (N + 1);                // N
    int* perm    = cursor + N;                       // EL

    const int TB = 256;
    const int gBN = (BN + TB - 1) / TB;
    const int gE  = (EL + TB - 1) / TB;

    // CSR build (edges constant across batches/layers)
    hipMemsetAsync(cursor, 0, N * sizeof(int), stream);
    count_kernel  <<<gE, TB, 0, stream>>>(ei, cursor);
    scan_kernel   <<<1, TB, 0, stream>>>(cursor, offsets);
    scatter_kernel<<<gE, TB, 0, stream>>>(ei, cursor, perm);

    // input projection
    proj_kernel<<<gBN, TB, 0, stream>>>(x, proj_w, proj_b, bufA);

    // GAT layer 0 (H=8) + ELU
    gemm_attn_kernel<8><<<gBN, TB, 0, stream>>>(bufA, g_w[0], g_as[0], g_ad[0], bufX, es, ed);
    agg_kernel<8, true><<<BN / 4, TB, 0, stream>>>(bufX, es, ed, offsets, perm, g_b[0], bufA);

    // GAT layer 1 (H=8) + ELU
    gemm_attn_kernel<8><<<gBN, TB, 0, stream>>>(bufA, g_w[1], g_as[1], g_ad[1], bufX, es, ed);
    agg_kernel<8, true><<<BN / 4, TB, 0, stream>>>(bufX, es, ed, offsets, perm, g_b[1], bufA);

    // GAT layer 2 (H=1), no ELU
    gemm_attn_kernel<1><<<gBN, TB, 0, stream>>>(bufA, g_w[2], g_as[2], g_ad[2], bufX, es, ed);
    agg_kernel<1, false><<<BN / 4, TB, 0, stream>>>(bufX, es, ed, offsets, perm, g_b[2], bufA);

    // conv1d(k=3) + relu + final projection, writes [B,3,N]
    conv_out_kernel<<<gBN, TB, 0, stream>>>(bufA, conv_w, conv_b, out_w, out_b, out);
}